// Round 4
// baseline (47.925 us; speedup 1.0000x reference)
//
#include <hip/hip_runtime.h>
#include <hip/hip_bf16.h>
#include <math.h>

typedef _Float16 f16x8 __attribute__((ext_vector_type(8)));
typedef _Float16 f16x4 __attribute__((ext_vector_type(4)));
typedef float    f32x4 __attribute__((ext_vector_type(4)));

#define VT_W 8448   // v16T row: [64 zero][b0:4096][128 zero][b1:4096][64 zero]

__device__ __host__ __forceinline__ int swz(int ch, int row) {
    return (ch & 24) | ((ch & 7) ^ (row & 7));
}
__device__ __forceinline__ void gld16(const void* g, void* l) {
    __builtin_amdgcn_global_load_lds((const __attribute__((address_space(1))) void*)g,
                                     (__attribute__((address_space(3))) void*)l, 16, 0, 0);
}
__device__ __forceinline__ f32x4 mfma16(f16x8 a, f16x8 b, f32x4 c) {
    return __builtin_amdgcn_mfma_f32_16x16x32_f16(a, b, c, 0, 0, 0);
}

// ---- weights fp32 -> fp16 (row-swizzled) + zero v16T guard bands
__global__ __launch_bounds__(256) void convw(const float* __restrict__ w1,
                                             const float* __restrict__ w2,
                                             const float* __restrict__ w3,
                                             const float* __restrict__ wo,
                                             _Float16* __restrict__ o1,
                                             _Float16* __restrict__ o2,
                                             _Float16* __restrict__ o3,
                                             _Float16* __restrict__ oo,
                                             _Float16* __restrict__ vT) {
    int gid = blockIdx.x * 256 + threadIdx.x;          // 32768 total
    if (gid < 8192) {                                   // guard zeroing: 256 rows x 32 chunks
        int row = gid >> 5, g = gid & 31;
        int col0 = (g < 8) ? g * 8 : (g < 24) ? 4160 + (g - 8) * 8 : 8384 + (g - 24) * 8;
        f16x8 z = {};
        *(f16x8*)&vT[(size_t)row * VT_W + col0] = z;
    }
    const float* src; _Float16* dst; int local;
    if (gid < 8192)       { src = w1; dst = o1; local = gid; }
    else if (gid < 16256) { src = w2; dst = o2; local = gid - 8192; }
    else if (gid < 16384) {                             // zero-fill w2 rows 252..255
        int l = gid - 16256;
        int row = 252 + (l >> 5), ch = l & 31;
        f16x8 z = {};
        *(f16x8*)&o2[row * 256 + ch * 8] = z;
        return;
    }
    else if (gid < 24576) { src = w3; dst = o3; local = gid - 16384; }
    else                  { src = wo; dst = oo; local = gid - 24576; }
    int row = local >> 5, ch = local & 31;
    float4 lo = *(const float4*)&src[row * 256 + ch * 8];
    float4 hi = *(const float4*)&src[row * 256 + ch * 8 + 4];
    f16x8 h = { (_Float16)lo.x, (_Float16)lo.y, (_Float16)lo.z, (_Float16)lo.w,
                (_Float16)hi.x, (_Float16)hi.y, (_Float16)hi.z, (_Float16)hi.w };
    *(f16x8*)&dst[row * 256 + swz(ch, row) * 8] = h;
}

// ---- fused G1+G2: 32-row blocks. query -> relu(q@w1^T) in LDS -> weight16 global
__global__ __launch_bounds__(256) void fused_qw(const float* __restrict__ query,
                                                const _Float16* __restrict__ w1s,
                                                const _Float16* __restrict__ w2s,
                                                _Float16* __restrict__ wgt) {
    __shared__ __align__(16) _Float16 Aq[32 * 256];   // 16 KB query fp16 (swizzled)
    __shared__ __align__(16) _Float16 Bt[64 * 256];   // 32 KB weight tile
    __shared__ __align__(16) _Float16 Qr[32 * 256];   // 16 KB q_relu (swizzled)
    const int tid = threadIdx.x, lane = tid & 63, wid = tid >> 6;
    const int m0 = blockIdx.x * 32;

    // stage query fp32 -> fp16 swizzled
    #pragma unroll
    for (int i = 0; i < 4; ++i) {
        int slot = i * 256 + tid;
        int row = slot >> 5, ch = slot & 31;
        const float* p = &query[(size_t)(m0 + row) * 256 + ch * 8];
        float4 lo = *(const float4*)p, hi = *(const float4*)(p + 4);
        f16x8 h = { (_Float16)lo.x, (_Float16)lo.y, (_Float16)lo.z, (_Float16)lo.w,
                    (_Float16)hi.x, (_Float16)hi.y, (_Float16)hi.z, (_Float16)hi.w };
        *(f16x8*)&Aq[row * 256 + swz(ch, row) * 8] = h;
    }

    // ---- phase 1: qrelu = relu(query @ w1^T) -> Qr (LDS)
    for (int nt = 0; nt < 4; ++nt) {
        const char* src = (const char*)w1s + nt * 32768;
        #pragma unroll
        for (int i = 0; i < 8; ++i) {
            int j = wid * 8 + i;
            gld16(src + j * 1024 + lane * 16, (char*)Bt + j * 1024);
        }
        __syncthreads();
        f32x4 acc[2] = {};
        #pragma unroll
        for (int ks = 0; ks < 8; ++ks) {
            int chn = ks * 4 + (lane >> 4);
            int brow = wid * 16 + (lane & 15);
            f16x8 bf = *(const f16x8*)&Bt[brow * 256 + swz(chn, brow) * 8];
            #pragma unroll
            for (int i = 0; i < 2; ++i) {
                int row = i * 16 + (lane & 15);
                f16x8 af = *(const f16x8*)&Aq[row * 256 + swz(chn, row) * 8];
                acc[i] = mfma16(af, bf, acc[i]);
            }
        }
        #pragma unroll
        for (int i = 0; i < 2; ++i)
            #pragma unroll
            for (int r = 0; r < 4; ++r) {
                int row = i * 16 + ((lane >> 4) << 2) + r;
                int n = nt * 64 + wid * 16 + (lane & 15);
                float v = fmaxf(acc[i][r], 0.f);
                Qr[row * 256 + swz(n >> 3, row) * 8 + (n & 7)] = (_Float16)v;
            }
        __syncthreads();
    }

    // ---- phase 2: weight = qrelu @ w2^T -> global
    for (int nt = 0; nt < 4; ++nt) {
        const char* src = (const char*)w2s + nt * 32768;
        #pragma unroll
        for (int i = 0; i < 8; ++i) {
            int j = wid * 8 + i;
            gld16(src + j * 1024 + lane * 16, (char*)Bt + j * 1024);
        }
        __syncthreads();
        f32x4 acc[2] = {};
        #pragma unroll
        for (int ks = 0; ks < 8; ++ks) {
            int chn = ks * 4 + (lane >> 4);
            int brow = wid * 16 + (lane & 15);
            f16x8 bf = *(const f16x8*)&Bt[brow * 256 + swz(chn, brow) * 8];
            #pragma unroll
            for (int i = 0; i < 2; ++i) {
                int row = i * 16 + (lane & 15);
                f16x8 af = *(const f16x8*)&Qr[row * 256 + swz(chn, row) * 8];
                acc[i] = mfma16(af, bf, acc[i]);
            }
        }
        #pragma unroll
        for (int i = 0; i < 2; ++i)
            #pragma unroll
            for (int r = 0; r < 4; ++r) {
                int m = m0 + i * 16 + ((lane >> 4) << 2) + r;
                int n = nt * 64 + wid * 16 + (lane & 15);
                wgt[(size_t)m * 256 + n] = (_Float16)acc[i][r];
            }
        __syncthreads();
    }
}

// ---- v GEMM with transposed epilogue: v16T[d][64 + b*128 + m] = (value @ w3^T)[m][d]
__global__ __launch_bounds__(256) void gemm_v(const float* __restrict__ value,
                                              const _Float16* __restrict__ w3s,
                                              _Float16* __restrict__ vT) {
    __shared__ __align__(16) _Float16 As[64 * 256];
    __shared__ __align__(16) _Float16 Bs[64 * 256];
    const int tid = threadIdx.x, lane = tid & 63, wid = tid >> 6;
    const int wm = wid >> 1, wn = wid & 1;
    const int m0 = blockIdx.x * 64;
    const int n0 = blockIdx.y * 64;

    {   // stage B (w3 rows n0.., pre-swizzled)
        const char* Bb = (const char*)w3s + (size_t)n0 * 512;
        #pragma unroll
        for (int i = 0; i < 8; ++i) {
            int j = wid * 8 + i;
            gld16(Bb + j * 1024 + lane * 16, (char*)Bs + j * 1024);
        }
    }
    {   // stage A: value fp32 -> fp16 swizzled
        #pragma unroll
        for (int i = 0; i < 8; ++i) {
            int slot = i * 256 + tid;
            int row = slot >> 5, ch = slot & 31;
            const float* p = &value[(size_t)(m0 + row) * 256 + ch * 8];
            float4 lo = *(const float4*)p, hi = *(const float4*)(p + 4);
            f16x8 h = { (_Float16)lo.x, (_Float16)lo.y, (_Float16)lo.z, (_Float16)lo.w,
                        (_Float16)hi.x, (_Float16)hi.y, (_Float16)hi.z, (_Float16)hi.w };
            *(f16x8*)&As[row * 256 + swz(ch, row) * 8] = h;
        }
    }
    __syncthreads();

    f32x4 acc[2][2] = {};
    #pragma unroll
    for (int ks = 0; ks < 8; ++ks) {
        int chn = ks * 4 + (lane >> 4);
        f16x8 af[2], bf[2];
        #pragma unroll
        for (int i = 0; i < 2; ++i) {
            int row = wm * 32 + i * 16 + (lane & 15);
            af[i] = *(const f16x8*)&As[row * 256 + swz(chn, row) * 8];
        }
        #pragma unroll
        for (int j = 0; j < 2; ++j) {
            int row = wn * 32 + j * 16 + (lane & 15);
            bf[j] = *(const f16x8*)&Bs[row * 256 + swz(chn, row) * 8];
        }
        #pragma unroll
        for (int i = 0; i < 2; ++i)
            #pragma unroll
            for (int j = 0; j < 2; ++j)
                acc[i][j] = mfma16(af[i], bf[j], acc[i][j]);
    }

    const int boff = 64 + ((m0 >= 4096) ? 128 : 0);
    #pragma unroll
    for (int i = 0; i < 2; ++i) {
        #pragma unroll
        for (int j = 0; j < 2; ++j) {
            int n  = n0 + wn * 32 + j * 16 + (lane & 15);
            int mb = m0 + wm * 32 + i * 16 + ((lane >> 4) << 2);
            f16x4 h = { (_Float16)acc[i][j][0], (_Float16)acc[i][j][1],
                        (_Float16)acc[i][j][2], (_Float16)acc[i][j][3] };
            *(f16x4*)&vT[(size_t)n * VT_W + boff + mb] = h;
        }
    }
}

// ---- fused attn + out GEMM. Block = (b, 32-t tile). Wave = head.
__global__ __launch_bounds__(256) void attn_out(const _Float16* __restrict__ wgt,
                                                const _Float16* __restrict__ vT,
                                                const _Float16* __restrict__ wos,
                                                float* __restrict__ outp) {
    __shared__ __align__(16) _Float16 vwT[256 * 104];   // 53248 B: V^T window, K pad 96->104
    __shared__ __align__(16) _Float16 Pl[4 * 32 * 104]; // 26624 B: banded softmax P
    __shared__ __align__(16) _Float16 wb[32 * 256];     // 16 KB: weight rows
    __shared__ __align__(16) _Float16 xb[32 * 256];     // 16 KB: x (swizzled)
    __shared__ __align__(16) _Float16 Bt[64 * 256];     // 32 KB: w_out tile
    const int tid = threadIdx.x, lane = tid & 63, wid = tid >> 6;
    const int bid = blockIdx.x;
    const int t0 = (bid & 127) * 32;
    const int b  = bid >> 7;
    const size_t rowb = (size_t)b * 4096;

    // stage V^T window: cols j = t0-32 .. t0+71 (13 chunks/row; chunk 12 pad, never read)
    {
        const int c0 = 32 + b * 4224 + t0;              // elem col of window start
        #pragma unroll
        for (int i = 0; i < 13; ++i) {
            int s = i * 256 + tid;
            int d = s / 13, ch = s % 13;
            gld16((const char*)vT + ((size_t)d * VT_W + c0 + ch * 8) * 2,
                  (char*)vwT + i * 4096 + wid * 1024);
        }
    }
    // stage weight rows t0..t0+31 (16 KB contiguous)
    {
        const char* src = (const char*)(wgt + (rowb + t0) * 256);
        #pragma unroll
        for (int i = 0; i < 4; ++i)
            gld16(src + (size_t)(i * 256 + tid) * 16, (char*)wb + i * 4096 + wid * 1024);
    }
    // stage w_out tile 0
    {
        #pragma unroll
        for (int i = 0; i < 8; ++i)
            gld16((const char*)wos + (size_t)(i * 256 + tid) * 16,
                  (char*)Bt + i * 4096 + wid * 1024);
    }
    // zero P band matrix
    #pragma unroll
    for (int i = 0; i < 7; ++i) {
        int s = i * 256 + tid;
        if (s < 1664) { f16x8 z = {}; *(f16x8*)&Pl[s * 8] = z; }
    }
    __syncthreads();

    // ---- softmax -> banded P. jl = tl + c + 1 (window starts at t0-32)
    const int h = wid;
    const int hf = lane >> 5, c = lane & 31;
    for (int i = 0; i < 16; ++i) {
        int tl = 2 * i + hf;
        int t  = t0 + tl;
        int c1 = c + 32;
        int j0 = t + c - 31, j1 = t + c1 - 31;
        bool ok0 = (j0 >= 0) && (j0 < 4096);
        bool ok1 = (c1 < 63) && (j1 >= 0) && (j1 < 4096);
        float s0 = ok0 ? (float)wb[tl * 256 + h * 63 + c]  : -INFINITY;
        float s1 = ok1 ? (float)wb[tl * 256 + h * 63 + c1] : -INFINITY;
        float mx = fmaxf(s0, s1);
        #pragma unroll
        for (int off = 16; off > 0; off >>= 1) mx = fmaxf(mx, __shfl_xor(mx, off));
        float e0 = ok0 ? __expf(s0 - mx) : 0.f;
        float e1 = ok1 ? __expf(s1 - mx) : 0.f;
        float sum = e0 + e1;
        #pragma unroll
        for (int off = 16; off > 0; off >>= 1) sum += __shfl_xor(sum, off);
        float inv = 1.0f / sum;
        Pl[(h * 32 + tl) * 104 + (tl + c + 1)] = (_Float16)(e0 * inv);
        if (c1 < 63) Pl[(h * 32 + tl) * 104 + (tl + c1 + 1)] = (_Float16)(e1 * inv);
    }
    __syncthreads();

    // ---- PV via MFMA: x[32][64] per wave (head strip), K = 96
    f32x4 xa[2][4] = {};
    #pragma unroll
    for (int ks = 0; ks < 3; ++ks) {
        int chn = ks * 4 + (lane >> 4);
        f16x8 af[2], bf[4];
        #pragma unroll
        for (int i = 0; i < 2; ++i)
            af[i] = *(const f16x8*)&Pl[(h * 32 + i * 16 + (lane & 15)) * 104 + chn * 8];
        #pragma unroll
        for (int j = 0; j < 4; ++j)
            bf[j] = *(const f16x8*)&vwT[(h * 64 + j * 16 + (lane & 15)) * 104 + chn * 8];
        #pragma unroll
        for (int i = 0; i < 2; ++i)
            #pragma unroll
            for (int j = 0; j < 4; ++j)
                xa[i][j] = mfma16(af[i], bf[j], xa[i][j]);
    }
    // x -> LDS fp16 swizzled
    #pragma unroll
    for (int i = 0; i < 2; ++i)
        #pragma unroll
        for (int j = 0; j < 4; ++j)
            #pragma unroll
            for (int r = 0; r < 4; ++r) {
                int row = i * 16 + ((lane >> 4) << 2) + r;
                int n   = h * 64 + j * 16 + (lane & 15);
                xb[row * 256 + swz(n >> 3, row) * 8 + (n & 7)] = (_Float16)xa[i][j][r];
            }

    // ---- out = x @ w_out^T (4 n-tiles, single-buffered Bt)
    for (int nt = 0; nt < 4; ++nt) {
        __syncthreads();    // Bt staged + (nt==0) xb written / prev reads done
        f32x4 oa[2] = {};
        #pragma unroll
        for (int ks = 0; ks < 8; ++ks) {
            int chn = ks * 4 + (lane >> 4);
            int brow = wid * 16 + (lane & 15);
            f16x8 bf = *(const f16x8*)&Bt[brow * 256 + swz(chn, brow) * 8];
            #pragma unroll
            for (int i = 0; i < 2; ++i) {
                int row = i * 16 + (lane & 15);
                f16x8 af = *(const f16x8*)&xb[row * 256 + swz(chn, row) * 8];
                oa[i] = mfma16(af, bf, oa[i]);
            }
        }
        #pragma unroll
        for (int i = 0; i < 2; ++i)
            #pragma unroll
            for (int r = 0; r < 4; ++r) {
                int m = (int)rowb + t0 + i * 16 + ((lane >> 4) << 2) + r;
                int n = nt * 64 + wid * 16 + (lane & 15);
                outp[(size_t)m * 256 + n] = oa[i][r];
            }
        if (nt < 3) {
            __syncthreads();
            const char* src = (const char*)wos + (size_t)(nt + 1) * 32768;
            #pragma unroll
            for (int i = 0; i < 8; ++i)
                gld16(src + (size_t)(i * 256 + tid) * 16, (char*)Bt + i * 4096 + wid * 1024);
        }
    }
}

extern "C" void kernel_launch(void* const* d_in, const int* in_sizes, int n_in,
                              void* d_out, int out_size, void* d_ws, size_t ws_size,
                              hipStream_t stream) {
    const float* query = (const float*)d_in[0];
    const float* value = (const float*)d_in[2];
    const float* w1    = (const float*)d_in[4];
    const float* w2    = (const float*)d_in[5];
    const float* w3    = (const float*)d_in[6];
    const float* w_out = (const float*)d_in[7];

    char* ws = (char*)d_ws;
    _Float16* wgt  = (_Float16*)ws;                         // 4 MB: weight16 [8192][256]
    _Float16* vT   = (_Float16*)(ws + (4u << 20));          // 4.125 MB: v16T [256][8448]
    _Float16* w1s  = (_Float16*)(ws + (9u << 20));          // 128 KB each
    _Float16* w2s  = w1s + 65536;
    _Float16* w3s  = w2s + 65536;
    _Float16* wos  = w3s + 65536;

    dim3 blk(256);
    convw<<<dim3(128), blk, 0, stream>>>(w1, w2, w3, w_out, w1s, w2s, w3s, wos, vT);
    fused_qw<<<dim3(256), blk, 0, stream>>>(query, w1s, w2s, wgt);
    gemm_v<<<dim3(128, 4), blk, 0, stream>>>(value, w3s, vT);
    attn_out<<<dim3(256), blk, 0, stream>>>(wgt, vT, wos, (float*)d_out);
}

// Round 5
// 42.024 us; speedup vs baseline: 1.1404x; 1.1404x over previous
//
#include <hip/hip_runtime.h>
#include <hip/hip_bf16.h>
#include <math.h>

typedef _Float16 f16x8 __attribute__((ext_vector_type(8)));
typedef _Float16 f16x4 __attribute__((ext_vector_type(4)));
typedef float    f32x4 __attribute__((ext_vector_type(4)));

#define VT_W 8448   // v16T row: [64 zero][b0:4096][128 zero][b1:4096][64 zero]

__device__ __host__ __forceinline__ int swz(int ch, int row) {
    return (ch & 24) | ((ch & 7) ^ (row & 7));
}
__device__ __forceinline__ void gld16(const void* g, void* l) {
    __builtin_amdgcn_global_load_lds((const __attribute__((address_space(1))) void*)g,
                                     (__attribute__((address_space(3))) void*)l, 16, 0, 0);
}
__device__ __forceinline__ f32x4 mfma16(f16x8 a, f16x8 b, f32x4 c) {
    return __builtin_amdgcn_mfma_f32_16x16x32_f16(a, b, c, 0, 0, 0);
}

// ---- weights fp32 -> fp16 packed MFMA-fragment-major: elem idx = ((nblk*8+ks)*64+lane)*8
// (lane&15 = n within 16-block, lane>>4 = k-subchunk). w2 rows >=252 zero. + vT guard zeros.
__global__ __launch_bounds__(256) void convw(const float* __restrict__ w1,
                                             const float* __restrict__ w2,
                                             const float* __restrict__ w3,
                                             const float* __restrict__ wo,
                                             _Float16* __restrict__ p1,
                                             _Float16* __restrict__ p2,
                                             _Float16* __restrict__ p3,
                                             _Float16* __restrict__ po,
                                             _Float16* __restrict__ vT) {
    int gid = blockIdx.x * 256 + threadIdx.x;          // 40960 total
    if (gid < 32768) {
        int widx = gid >> 13;
        int r    = gid & 8191;
        int lane = r & 63;
        int ks   = (r >> 6) & 7;
        int nblk = r >> 9;
        int n  = nblk * 16 + (lane & 15);
        int kc = (ks * 4 + (lane >> 4)) * 8;
        const float* src = widx == 0 ? w1 : widx == 1 ? w2 : widx == 2 ? w3 : wo;
        _Float16*    dst = widx == 0 ? p1 : widx == 1 ? p2 : widx == 2 ? p3 : po;
        f16x8 h = {};
        if (!(widx == 1 && n >= 252)) {
            float4 lo = *(const float4*)&src[n * 256 + kc];
            float4 hi = *(const float4*)&src[n * 256 + kc + 4];
            h[0] = (_Float16)lo.x; h[1] = (_Float16)lo.y; h[2] = (_Float16)lo.z; h[3] = (_Float16)lo.w;
            h[4] = (_Float16)hi.x; h[5] = (_Float16)hi.y; h[6] = (_Float16)hi.z; h[7] = (_Float16)hi.w;
        }
        *(f16x8*)&dst[r * 8] = h;
    } else {
        int g = gid - 32768;                            // 8192 guard-zero threads
        int row = g >> 5, gg = g & 31;
        int col0 = (gg < 8) ? gg * 8 : (gg < 24) ? 4160 + (gg - 8) * 8 : 8384 + (gg - 24) * 8;
        f16x8 z = {};
        *(f16x8*)&vT[(size_t)row * VT_W + col0] = z;
    }
}

// ---- producer: blocks 0..255 type-A (wgt = relu(q@w1^T)@w2^T, 32 rows each),
//                blocks 256..767 type-B (vT = (value@w3^T)^T, 64x64 tiles).
// 32 KB LDS -> up to 5 blocks/CU; B-operands read as packed fragments from global (L2).
__global__ __launch_bounds__(256) void produce(const float* __restrict__ query,
                                               const float* __restrict__ value,
                                               const _Float16* __restrict__ w1p,
                                               const _Float16* __restrict__ w2p,
                                               const _Float16* __restrict__ w3p,
                                               _Float16* __restrict__ wgt,
                                               _Float16* __restrict__ vT) {
    __shared__ __align__(16) _Float16 lds[16384];       // 32 KB
    const int tid = threadIdx.x, lane = tid & 63, wid = tid >> 6;
    const int bid = blockIdx.x;

    if (bid < 256) {
        // ================= type A =================
        _Float16* Aq = lds;          // [32][256] swizzled
        _Float16* Qr = lds + 8192;   // [32][256] swizzled
        const int m0 = bid * 32;

        #pragma unroll
        for (int i = 0; i < 4; ++i) {
            int slot = i * 256 + tid;
            int row = slot >> 5, ch = slot & 31;
            const float* p = &query[(size_t)(m0 + row) * 256 + ch * 8];
            float4 lo = *(const float4*)p, hi = *(const float4*)(p + 4);
            f16x8 h = { (_Float16)lo.x, (_Float16)lo.y, (_Float16)lo.z, (_Float16)lo.w,
                        (_Float16)hi.x, (_Float16)hi.y, (_Float16)hi.z, (_Float16)hi.w };
            *(f16x8*)&Aq[row * 256 + swz(ch, row) * 8] = h;
        }
        __syncthreads();

        // G1: wave = 32m x 64n strip (n0 = wid*64)
        {
            f32x4 acc[2][4] = {};
            #pragma unroll
            for (int ks = 0; ks < 8; ++ks) {
                int chn = ks * 4 + (lane >> 4);
                f16x8 af[2], bf[4];
                #pragma unroll
                for (int i = 0; i < 2; ++i) {
                    int row = i * 16 + (lane & 15);
                    af[i] = *(const f16x8*)&Aq[row * 256 + swz(chn, row) * 8];
                }
                #pragma unroll
                for (int j = 0; j < 4; ++j)
                    bf[j] = *(const f16x8*)&w1p[(((wid * 4 + j) * 8 + ks) * 64 + lane) * 8];
                #pragma unroll
                for (int i = 0; i < 2; ++i)
                    #pragma unroll
                    for (int j = 0; j < 4; ++j)
                        acc[i][j] = mfma16(af[i], bf[j], acc[i][j]);
            }
            #pragma unroll
            for (int i = 0; i < 2; ++i)
                #pragma unroll
                for (int j = 0; j < 4; ++j)
                    #pragma unroll
                    for (int r = 0; r < 4; ++r) {
                        int row = i * 16 + ((lane >> 4) << 2) + r;
                        int n   = wid * 64 + j * 16 + (lane & 15);
                        float v = fmaxf(acc[i][j][r], 0.f);
                        Qr[row * 256 + swz(n >> 3, row) * 8 + (n & 7)] = (_Float16)v;
                    }
        }
        __syncthreads();

        // G2: wgt rows m0..m0+31
        {
            f32x4 acc[2][4] = {};
            #pragma unroll
            for (int ks = 0; ks < 8; ++ks) {
                int chn = ks * 4 + (lane >> 4);
                f16x8 af[2], bf[4];
                #pragma unroll
                for (int i = 0; i < 2; ++i) {
                    int row = i * 16 + (lane & 15);
                    af[i] = *(const f16x8*)&Qr[row * 256 + swz(chn, row) * 8];
                }
                #pragma unroll
                for (int j = 0; j < 4; ++j)
                    bf[j] = *(const f16x8*)&w2p[(((wid * 4 + j) * 8 + ks) * 64 + lane) * 8];
                #pragma unroll
                for (int i = 0; i < 2; ++i)
                    #pragma unroll
                    for (int j = 0; j < 4; ++j)
                        acc[i][j] = mfma16(af[i], bf[j], acc[i][j]);
            }
            #pragma unroll
            for (int i = 0; i < 2; ++i)
                #pragma unroll
                for (int j = 0; j < 4; ++j)
                    #pragma unroll
                    for (int r = 0; r < 4; ++r) {
                        int m = m0 + i * 16 + ((lane >> 4) << 2) + r;
                        int n = wid * 64 + j * 16 + (lane & 15);
                        wgt[(size_t)m * 256 + n] = (_Float16)acc[i][j][r];
                    }
        }
    } else {
        // ================= type B =================
        _Float16* As = lds;          // [64][256] swizzled
        const int b2 = bid - 256;
        const int m0 = (b2 >> 2) * 64;
        const int nb = b2 & 3;
        const int wm = wid >> 1, wn = wid & 1;

        #pragma unroll
        for (int i = 0; i < 8; ++i) {
            int slot = i * 256 + tid;
            int row = slot >> 5, ch = slot & 31;
            const float* p = &value[(size_t)(m0 + row) * 256 + ch * 8];
            float4 lo = *(const float4*)p, hi = *(const float4*)(p + 4);
            f16x8 h = { (_Float16)lo.x, (_Float16)lo.y, (_Float16)lo.z, (_Float16)lo.w,
                        (_Float16)hi.x, (_Float16)hi.y, (_Float16)hi.z, (_Float16)hi.w };
            *(f16x8*)&As[row * 256 + swz(ch, row) * 8] = h;
        }
        __syncthreads();

        f32x4 acc[2][2] = {};
        #pragma unroll
        for (int ks = 0; ks < 8; ++ks) {
            int chn = ks * 4 + (lane >> 4);
            f16x8 af[2], bf[2];
            #pragma unroll
            for (int i = 0; i < 2; ++i) {
                int row = wm * 32 + i * 16 + (lane & 15);
                af[i] = *(const f16x8*)&As[row * 256 + swz(chn, row) * 8];
            }
            #pragma unroll
            for (int j = 0; j < 2; ++j) {
                int nblk = nb * 4 + wn * 2 + j;
                bf[j] = *(const f16x8*)&w3p[((nblk * 8 + ks) * 64 + lane) * 8];
            }
            #pragma unroll
            for (int i = 0; i < 2; ++i)
                #pragma unroll
                for (int j = 0; j < 2; ++j)
                    acc[i][j] = mfma16(af[i], bf[j], acc[i][j]);
        }

        const int boff = 64 + ((m0 >= 4096) ? 128 : 0);
        #pragma unroll
        for (int i = 0; i < 2; ++i)
            #pragma unroll
            for (int j = 0; j < 2; ++j) {
                int n  = nb * 64 + wn * 32 + j * 16 + (lane & 15);
                int mb = m0 + wm * 32 + i * 16 + ((lane >> 4) << 2);
                f16x4 h = { (_Float16)acc[i][j][0], (_Float16)acc[i][j][1],
                            (_Float16)acc[i][j][2], (_Float16)acc[i][j][3] };
                *(f16x4*)&vT[(size_t)n * VT_W + boff + mb] = h;
            }
    }
}

// ---- fused attn + out GEMM. Block = (b, 16-t tile), wave = head. 74.75 KB LDS -> 2 blocks/CU.
__global__ __launch_bounds__(256) void attn_out(const _Float16* __restrict__ wgt,
                                                const _Float16* __restrict__ vT,
                                                const _Float16* __restrict__ wop,
                                                float* __restrict__ outp) {
    __shared__ __align__(16) _Float16 vwT[256 * 104];   // 53248 B (window jwin 0..103, j = t0-32+jwin)
    __shared__ __align__(16) _Float16 Pl[64 * 104];     // 13312 B banded P (rows = h*16+tl)
    __shared__ __align__(16) _Float16 xb[16 * 256];     // 8192 B x tile (swizzled)
    const int tid = threadIdx.x, lane = tid & 63, wid = tid >> 6;
    const int bid = blockIdx.x;
    const int t0 = (bid & 255) * 16;
    const int b  = bid >> 8;
    const size_t rowb = (size_t)b * 4096;

    // stage V^T window: 13 16B-chunks per d-row; LDS linear == row-major stride 104
    {
        const int c0 = 32 + b * 4224 + t0;   // vT element col of jwin==0
        #pragma unroll
        for (int i = 0; i < 13; ++i) {
            int s = i * 256 + tid;
            int d = s / 13, ch = s % 13;
            gld16((const char*)vT + ((size_t)d * VT_W + c0 + ch * 8) * 2,
                  (char*)vwT + (i * 256 + wid * 64) * 16);
        }
    }
    // zero P band matrix (64 rows x 104)
    #pragma unroll
    for (int i = 0; i < 4; ++i) {
        int s = i * 256 + tid;
        if (s < 832) { f16x8 z = {}; *(f16x8*)&Pl[s * 8] = z; }
    }
    __syncthreads();

    // softmax: wave = head h; 16 t's, 2 per iter; scores straight from global (L2)
    const int h = wid, hf = lane >> 5, c = lane & 31;
    #pragma unroll
    for (int i = 0; i < 8; ++i) {
        int tl = 2 * i + hf;
        int t  = t0 + tl;
        int c1 = c + 32;
        int j0 = t + c - 31, j1 = t + c1 - 31;
        bool ok0 = (j0 >= 0) && (j0 < 4096);
        bool ok1 = (c1 < 63) && (j1 >= 0) && (j1 < 4096);
        const _Float16* wrow = wgt + (rowb + t) * 256 + h * 63;
        float s0 = ok0 ? (float)wrow[c]  : -INFINITY;
        float s1 = ok1 ? (float)wrow[c1] : -INFINITY;
        float mx = fmaxf(s0, s1);
        #pragma unroll
        for (int off = 16; off > 0; off >>= 1) mx = fmaxf(mx, __shfl_xor(mx, off));
        float e0 = ok0 ? __expf(s0 - mx) : 0.f;
        float e1 = ok1 ? __expf(s1 - mx) : 0.f;
        float sum = e0 + e1;
        #pragma unroll
        for (int off = 16; off > 0; off >>= 1) sum += __shfl_xor(sum, off);
        float inv = 1.0f / sum;
        Pl[(h * 16 + tl) * 104 + (tl + c + 1)] = (_Float16)(e0 * inv);
        if (c1 < 63) Pl[(h * 16 + tl) * 104 + (tl + c1 + 1)] = (_Float16)(e1 * inv);
    }
    __syncthreads();

    // PV: wave = head; out 16t x 64d (1x4 tiles), K = 96 (cols >78 all-zero in Pl)
    {
        f32x4 xa[4] = {};
        #pragma unroll
        for (int ks = 0; ks < 3; ++ks) {
            int chn = ks * 4 + (lane >> 4);
            f16x8 af = *(const f16x8*)&Pl[(h * 16 + (lane & 15)) * 104 + chn * 8];
            #pragma unroll
            for (int j = 0; j < 4; ++j) {
                f16x8 bf = *(const f16x8*)&vwT[(h * 64 + j * 16 + (lane & 15)) * 104 + chn * 8];
                xa[j] = mfma16(af, bf, xa[j]);
            }
        }
        #pragma unroll
        for (int j = 0; j < 4; ++j)
            #pragma unroll
            for (int r = 0; r < 4; ++r) {
                int row = ((lane >> 4) << 2) + r;
                int n   = h * 64 + j * 16 + (lane & 15);
                xb[row * 256 + swz(n >> 3, row) * 8 + (n & 7)] = (_Float16)xa[j][r];
            }
    }
    __syncthreads();

    // G5: out = x @ w_out^T; wave = 64n strip (n0 = wid*64), bf packed from global
    {
        f32x4 oa[4] = {};
        #pragma unroll
        for (int ks = 0; ks < 8; ++ks) {
            int chn = ks * 4 + (lane >> 4);
            int row = lane & 15;
            f16x8 af = *(const f16x8*)&xb[row * 256 + swz(chn, row) * 8];
            #pragma unroll
            for (int j = 0; j < 4; ++j) {
                f16x8 bf = *(const f16x8*)&wop[(((wid * 4 + j) * 8 + ks) * 64 + lane) * 8];
                oa[j] = mfma16(af, bf, oa[j]);
            }
        }
        #pragma unroll
        for (int j = 0; j < 4; ++j)
            #pragma unroll
            for (int r = 0; r < 4; ++r) {
                int m = t0 + ((lane >> 4) << 2) + r;
                int n = wid * 64 + j * 16 + (lane & 15);
                outp[(rowb + m) * 256 + n] = oa[j][r];
            }
    }
}

extern "C" void kernel_launch(void* const* d_in, const int* in_sizes, int n_in,
                              void* d_out, int out_size, void* d_ws, size_t ws_size,
                              hipStream_t stream) {
    const float* query = (const float*)d_in[0];
    const float* value = (const float*)d_in[2];
    const float* w1    = (const float*)d_in[4];
    const float* w2    = (const float*)d_in[5];
    const float* w3    = (const float*)d_in[6];
    const float* w_out = (const float*)d_in[7];

    char* ws = (char*)d_ws;
    _Float16* wgt = (_Float16*)ws;                      // 4 MB: weight16 [8192][256]
    _Float16* vT  = (_Float16*)(ws + (4u << 20));       // 4.125 MB: v16T [256][8448]
    _Float16* w1p = (_Float16*)(ws + (9u << 20));       // 128 KB each, fragment-packed
    _Float16* w2p = w1p + 65536;
    _Float16* w3p = w2p + 65536;
    _Float16* wop = w3p + 65536;

    dim3 blk(256);
    convw<<<dim3(160), blk, 0, stream>>>(w1, w2, w3, w_out, w1p, w2p, w3p, wop, vT);
    produce<<<dim3(768), blk, 0, stream>>>(query, value, w1p, w2p, w3p, wgt, vT);
    attn_out<<<dim3(512), blk, 0, stream>>>(wgt, vT, wop, (float*)d_out);
}

// Round 7
// 28.628 us; speedup vs baseline: 1.6741x; 1.4679x over previous
//
#include <hip/hip_runtime.h>
#include <hip/hip_bf16.h>
#include <math.h>

typedef _Float16 f16x8 __attribute__((ext_vector_type(8)));
typedef _Float16 f16x4 __attribute__((ext_vector_type(4)));
typedef float    f32x4 __attribute__((ext_vector_type(4)));

__device__ __host__ __forceinline__ int swz(int ch, int row) {
    return (ch & 24) | ((ch & 7) ^ (row & 7));
}
__device__ __forceinline__ f32x4 mfma16(f16x8 a, f16x8 b, f32x4 c) {
    return __builtin_amdgcn_mfma_f32_16x16x32_f16(a, b, c, 0, 0, 0);
}
__device__ __forceinline__ f16x8 cvt8(float4 lo, float4 hi) {
    f16x8 r = { (_Float16)lo.x, (_Float16)lo.y, (_Float16)lo.z, (_Float16)lo.w,
                (_Float16)hi.x, (_Float16)hi.y, (_Float16)hi.z, (_Float16)hi.w };
    return r;
}

// ---- weights fp32 -> fp16, MFMA-B-fragment-major: dst[((nblk*8+ks)*64+lane)*8]
// holds w[nblk*16 + (lane&15)][(ks*4+(lane>>4))*8 .. +7]. w2 rows >= 252 zeroed.
__global__ __launch_bounds__(256) void convw(const float* __restrict__ w1,
                                             const float* __restrict__ w2,
                                             const float* __restrict__ w3,
                                             const float* __restrict__ wo,
                                             _Float16* __restrict__ p1,
                                             _Float16* __restrict__ p2,
                                             _Float16* __restrict__ p3,
                                             _Float16* __restrict__ po) {
    int gid = blockIdx.x * 256 + threadIdx.x;          // 32768 total
    int widx = gid >> 13;
    int r    = gid & 8191;
    int lane = r & 63;
    int ks   = (r >> 6) & 7;
    int nblk = r >> 9;
    int n  = nblk * 16 + (lane & 15);
    int kc = (ks * 4 + (lane >> 4)) * 8;
    const float* src = widx == 0 ? w1 : widx == 1 ? w2 : widx == 2 ? w3 : wo;
    _Float16*    dst = widx == 0 ? p1 : widx == 1 ? p2 : widx == 2 ? p3 : po;
    f16x8 h = {};
    if (!(widx == 1 && n >= 252)) {
        float4 lo = *(const float4*)&src[n * 256 + kc];
        float4 hi = *(const float4*)&src[n * 256 + kc + 4];
        h = cvt8(lo, hi);
    }
    *(f16x8*)&dst[r * 8] = h;
}

// ---- mono-kernel: block = 32 t's of one batch. 512 threads (8 waves), 1 block/CU.
// Phases: stage -> G1 -> G2(scores in LDS) + G3(halo 96 rows -> vwT in LDS, transposed)
//         -> softmax(banded P) -> PV -> G5 -> out. No global intermediates.
__global__ __launch_bounds__(512, 2) void mono(const float* __restrict__ query,
                                               const float* __restrict__ value,
                                               const _Float16* __restrict__ w1p,
                                               const _Float16* __restrict__ w2p,
                                               const _Float16* __restrict__ w3p,
                                               const _Float16* __restrict__ wop,
                                               float* __restrict__ outp) {
    __shared__ __align__(16) _Float16 RA[16384];   // Aq[32][256] + Qr[32][256]; later Pl[4*32][104]
    __shared__ __align__(16) _Float16 RB[8192];    // scores[32][256]; later xb[32][256]
    __shared__ __align__(16) _Float16 Vs[24576];   // value window [96][256] swz
    __shared__ __align__(16) _Float16 vwT[26624];  // v^T window [256 d][104 jwin]

    const int tid = threadIdx.x, lane = tid & 63, wid = tid >> 6;
    const int bidr = blockIdx.x;
    const int work = (bidr & 7) * 32 + (bidr >> 3);   // XCD-chunked: neighbors share halo L2
    const int b   = work >> 7;
    const int t0  = (work & 127) * 32;                // local t
    const size_t rowb = (size_t)b * 4096;

    _Float16* Aq = RA;
    _Float16* Qr = RA + 8192;
    _Float16* Pl = RA;            // valid after G2 (RA dead)
    _Float16* sc = RB;
    _Float16* xb = RB;            // valid after softmax (scores dead)

    // ---- stage: query 32 rows -> Aq; value 96 halo rows (clamped) -> Vs
    #pragma unroll
    for (int it = 0; it < 2; ++it) {
        int slot = it * 512 + tid;
        int row = slot >> 5, ch = slot & 31;
        const float* p = &query[(rowb + t0 + row) * 256 + ch * 8];
        float4 lo = *(const float4*)p, hi = *(const float4*)(p + 4);
        *(f16x8*)&Aq[row * 256 + swz(ch, row) * 8] = cvt8(lo, hi);
    }
    #pragma unroll
    for (int it = 0; it < 6; ++it) {
        int slot = it * 512 + tid;
        int row = slot >> 5, ch = slot & 31;
        int jl = t0 - 32 + row;
        jl = jl < 0 ? 0 : (jl > 4095 ? 4095 : jl);    // clamped; P=0 kills invalid cols
        const float* p = &value[(rowb + jl) * 256 + ch * 8];
        float4 lo = *(const float4*)p, hi = *(const float4*)(p + 4);
        *(f16x8*)&Vs[row * 256 + swz(ch, row) * 8] = cvt8(lo, hi);
    }
    __syncthreads();

    // ---- G1: Qr = relu(q @ w1^T). Wave = 32n strip (n0 = wid*32).
    {
        f32x4 acc[2][2] = {};
        #pragma unroll
        for (int ks = 0; ks < 8; ++ks) {
            int chn = ks * 4 + (lane >> 4);
            f16x8 af[2], bf[2];
            #pragma unroll
            for (int i = 0; i < 2; ++i) {
                int row = i * 16 + (lane & 15);
                af[i] = *(const f16x8*)&Aq[row * 256 + swz(chn, row) * 8];
            }
            #pragma unroll
            for (int j = 0; j < 2; ++j)
                bf[j] = *(const f16x8*)&w1p[(((wid * 2 + j) * 8 + ks) * 64 + lane) * 8];
            #pragma unroll
            for (int i = 0; i < 2; ++i)
                #pragma unroll
                for (int j = 0; j < 2; ++j)
                    acc[i][j] = mfma16(af[i], bf[j], acc[i][j]);
        }
        #pragma unroll
        for (int i = 0; i < 2; ++i)
            #pragma unroll
            for (int j = 0; j < 2; ++j)
                #pragma unroll
                for (int r = 0; r < 4; ++r) {
                    int row = i * 16 + ((lane >> 4) << 2) + r;
                    int n   = wid * 32 + j * 16 + (lane & 15);
                    float v = fmaxf(acc[i][j][r], 0.f);
                    Qr[row * 256 + swz(n >> 3, row) * 8 + (n & 7)] = (_Float16)v;
                }
    }
    __syncthreads();

    // ---- G2: scores = Qr @ w2^T -> sc (natural layout)
    {
        f32x4 acc[2][2] = {};
        #pragma unroll
        for (int ks = 0; ks < 8; ++ks) {
            int chn = ks * 4 + (lane >> 4);
            f16x8 af[2], bf[2];
            #pragma unroll
            for (int i = 0; i < 2; ++i) {
                int row = i * 16 + (lane & 15);
                af[i] = *(const f16x8*)&Qr[row * 256 + swz(chn, row) * 8];
            }
            #pragma unroll
            for (int j = 0; j < 2; ++j)
                bf[j] = *(const f16x8*)&w2p[(((wid * 2 + j) * 8 + ks) * 64 + lane) * 8];
            #pragma unroll
            for (int i = 0; i < 2; ++i)
                #pragma unroll
                for (int j = 0; j < 2; ++j)
                    acc[i][j] = mfma16(af[i], bf[j], acc[i][j]);
        }
        #pragma unroll
        for (int i = 0; i < 2; ++i)
            #pragma unroll
            for (int j = 0; j < 2; ++j)
                #pragma unroll
                for (int r = 0; r < 4; ++r) {
                    int row = i * 16 + ((lane >> 4) << 2) + r;
                    int n   = wid * 32 + j * 16 + (lane & 15);
                    sc[row * 256 + n] = (_Float16)acc[i][j][r];
                }
    }

    // ---- G3: vwT[d][jwin] = (Vs @ w3^T)^T for 96 halo rows. Wave = 32d strip.
    {
        f32x4 a3[6][2] = {};
        #pragma unroll
        for (int ks = 0; ks < 8; ++ks) {
            int chn = ks * 4 + (lane >> 4);
            f16x8 bf[2];
            #pragma unroll
            for (int j = 0; j < 2; ++j)
                bf[j] = *(const f16x8*)&w3p[(((wid * 2 + j) * 8 + ks) * 64 + lane) * 8];
            #pragma unroll
            for (int mi = 0; mi < 6; ++mi) {
                int row = mi * 16 + (lane & 15);
                f16x8 af = *(const f16x8*)&Vs[row * 256 + swz(chn, row) * 8];
                #pragma unroll
                for (int j = 0; j < 2; ++j)
                    a3[mi][j] = mfma16(af, bf[j], a3[mi][j]);
            }
        }
        #pragma unroll
        for (int mi = 0; mi < 6; ++mi)
            #pragma unroll
            for (int j = 0; j < 2; ++j) {
                int d  = wid * 32 + j * 16 + (lane & 15);
                int jw = mi * 16 + ((lane >> 4) << 2);
                f16x4 h = { (_Float16)a3[mi][j][0], (_Float16)a3[mi][j][1],
                            (_Float16)a3[mi][j][2], (_Float16)a3[mi][j][3] };
                *(f16x4*)&vwT[d * 104 + jw] = h;
            }
    }
    __syncthreads();   // scores + vwT ready; RA (Aq/Qr) dead -> Pl

    // ---- zero Pl (wave-local rows only: wave owns 16 t-rows of its head)
    const int h = wid >> 1, half = wid & 1;
    #pragma unroll
    for (int it = 0; it < 4; ++it) {
        int s = it * 64 + lane;
        if (s < 208) {                       // 16 rows * 13 chunks
            int rr = h * 32 + half * 16 + s / 13;
            int cc = s % 13;
            f16x8 z = {};
            *(f16x8*)&Pl[rr * 104 + cc * 8] = z;
        }
    }

    // ---- softmax -> banded P (wave-local). jwin = tl + c + 1
    {
        const int hf = lane >> 5, c = lane & 31;
        #pragma unroll
        for (int i = 0; i < 8; ++i) {
            int tl = half * 16 + 2 * i + hf;
            int t  = t0 + tl;
            int c1 = c + 32;
            int j0 = t + c - 31, j1 = t + c1 - 31;
            bool ok0 = (j0 >= 0) && (j0 < 4096);
            bool ok1 = (c1 < 63) && (j1 >= 0) && (j1 < 4096);
            float s0 = ok0 ? (float)sc[tl * 256 + h * 63 + c]  : -INFINITY;
            float s1 = ok1 ? (float)sc[tl * 256 + h * 63 + c1] : -INFINITY;
            float mx = fmaxf(s0, s1);
            #pragma unroll
            for (int off = 16; off > 0; off >>= 1) mx = fmaxf(mx, __shfl_xor(mx, off));
            float e0 = ok0 ? __expf(s0 - mx) : 0.f;
            float e1 = ok1 ? __expf(s1 - mx) : 0.f;
            float sum = e0 + e1;
            #pragma unroll
            for (int off = 16; off > 0; off >>= 1) sum += __shfl_xor(sum, off);
            float inv = 1.0f / sum;
            Pl[(h * 32 + tl) * 104 + (tl + c + 1)] = (_Float16)(e0 * inv);
            if (c1 < 63) Pl[(h * 32 + tl) * 104 + (tl + c1 + 1)] = (_Float16)(e1 * inv);
        }
    }
    __syncthreads();   // all softmax reads of sc done -> xb may overwrite RB

    // ---- PV: x[16t][64d] per wave (head h, half), K = 96
    {
        f32x4 xa[4] = {};
        #pragma unroll
        for (int ks = 0; ks < 3; ++ks) {
            int chn = ks * 4 + (lane >> 4);
            f16x8 af = *(const f16x8*)&Pl[(h * 32 + half * 16 + (lane & 15)) * 104 + chn * 8];
            #pragma unroll
            for (int j = 0; j < 4; ++j) {
                f16x8 bf = *(const f16x8*)&vwT[(h * 64 + j * 16 + (lane & 15)) * 104 + chn * 8];
                xa[j] = mfma16(af, bf, xa[j]);
            }
        }
        #pragma unroll
        for (int j = 0; j < 4; ++j)
            #pragma unroll
            for (int r = 0; r < 4; ++r) {
                int row = half * 16 + ((lane >> 4) << 2) + r;
                int n   = h * 64 + j * 16 + (lane & 15);
                xb[row * 256 + swz(n >> 3, row) * 8 + (n & 7)] = (_Float16)xa[j][r];
            }
    }
    __syncthreads();

    // ---- G5: out = x @ w_out^T
    {
        f32x4 oa[2][2] = {};
        #pragma unroll
        for (int ks = 0; ks < 8; ++ks) {
            int chn = ks * 4 + (lane >> 4);
            f16x8 af[2], bf[2];
            #pragma unroll
            for (int i = 0; i < 2; ++i) {
                int row = i * 16 + (lane & 15);
                af[i] = *(const f16x8*)&xb[row * 256 + swz(chn, row) * 8];
            }
            #pragma unroll
            for (int j = 0; j < 2; ++j)
                bf[j] = *(const f16x8*)&wop[(((wid * 2 + j) * 8 + ks) * 64 + lane) * 8];
            #pragma unroll
            for (int i = 0; i < 2; ++i)
                #pragma unroll
                for (int j = 0; j < 2; ++j)
                    oa[i][j] = mfma16(af[i], bf[j], oa[i][j]);
        }
        #pragma unroll
        for (int i = 0; i < 2; ++i)
            #pragma unroll
            for (int j = 0; j < 2; ++j)
                #pragma unroll
                for (int r = 0; r < 4; ++r) {
                    int m = t0 + i * 16 + ((lane >> 4) << 2) + r;
                    int n = wid * 32 + j * 16 + (lane & 15);
                    outp[(rowb + m) * 256 + n] = oa[i][j][r];
                }
    }
}

extern "C" void kernel_launch(void* const* d_in, const int* in_sizes, int n_in,
                              void* d_out, int out_size, void* d_ws, size_t ws_size,
                              hipStream_t stream) {
    const float* query = (const float*)d_in[0];
    const float* value = (const float*)d_in[2];
    const float* w1    = (const float*)d_in[4];
    const float* w2    = (const float*)d_in[5];
    const float* w3    = (const float*)d_in[6];
    const float* w_out = (const float*)d_in[7];

    char* ws = (char*)d_ws;
    _Float16* w1p = (_Float16*)ws;                    // 128 KB each, fragment-packed
    _Float16* w2p = w1p + 65536;
    _Float16* w3p = w2p + 65536;
    _Float16* wop = w3p + 65536;

    convw<<<dim3(128), dim3(256), 0, stream>>>(w1, w2, w3, w_out, w1p, w2p, w3p, wop);
    mono<<<dim3(256), dim3(512), 0, stream>>>(query, value, w1p, w2p, w3p, wop, (float*)d_out);
}